// Round 10
// baseline (90.193 us; speedup 1.0000x reference)
//
#include <hip/hip_runtime.h>

typedef float f32x4   __attribute__((ext_vector_type(4)));
typedef float f32x16  __attribute__((ext_vector_type(16)));
typedef int   i32x4   __attribute__((ext_vector_type(4)));
typedef int   i32x8   __attribute__((ext_vector_type(8)));

__device__ inline void gload_lds16(const void* g, void* l) {
    __builtin_amdgcn_global_load_lds((const __attribute__((address_space(1))) void*)g,
                                     (__attribute__((address_space(3))) void*)l,
                                     16, 0, 0);
}

// f32 -> fp4 e2m1 (RNE via threshold ladder): values {0,.5,1,1.5,2,3,4,6}
__device__ inline unsigned int enc_fp4(float v) {
    float a = fabsf(v);
    unsigned int c = (unsigned int)(a > 0.25f) + (a > 0.75f) + (a > 1.25f) +
                     (a > 1.75f) + (a > 2.5f)  + (a > 3.5f)  + (a > 5.0f);
    return c | ((v < 0.f) ? 8u : 0u);
}

// ---- pass 1: {x, mu} f32 -> fp4, plus exact f32 sum-of-squares per row ----
__global__ __launch_bounds__(256) void convert_kernel(
        const float* __restrict__ x, const float* __restrict__ mu,
        unsigned int* __restrict__ x4, unsigned int* __restrict__ mu4,
        float* __restrict__ x_sq, float* __restrict__ mu_sq,
        int D, int N, int C, int Cpad) {
    const int bid = blockIdx.x;
    const int t = threadIdx.x;
    const bool isX = bid < N;
    const int r = isX ? bid : bid - N;

    unsigned int* out = (isX ? x4 : mu4) + (size_t)r * (D / 8) + t;
    if (!isX && r >= C) {
        *out = 0u;
        if (t == 0) mu_sq[r] = 0.f;
        return;
    }
    const float* src = (isX ? x + (size_t)r * D : mu + (size_t)r * D) + t * 8;
    float4 v0 = *(const float4*)(src);
    float4 v1 = *(const float4*)(src + 4);
    float acc = v0.x * v0.x + v0.y * v0.y + v0.z * v0.z + v0.w * v0.w
              + v1.x * v1.x + v1.y * v1.y + v1.z * v1.z + v1.w * v1.w;
    unsigned int p = enc_fp4(v0.x) | (enc_fp4(v0.y) << 4) | (enc_fp4(v0.z) << 8)
                   | (enc_fp4(v0.w) << 12) | (enc_fp4(v1.x) << 16)
                   | (enc_fp4(v1.y) << 20) | (enc_fp4(v1.z) << 24)
                   | (enc_fp4(v1.w) << 28);
    *out = p;

    for (int off = 32; off; off >>= 1) acc += __shfl_down(acc, off, 64);
    __shared__ float sbuf[4];
    if ((t & 63) == 0) sbuf[t >> 6] = acc;
    __syncthreads();
    if (t == 0) {
        float s = sbuf[0] + sbuf[1] + sbuf[2] + sbuf[3];
        if (isX) x_sq[r] = s; else mu_sq[r] = s;
    }
}

// ---- pass 2: 256x256 fp4 GEMM via mfma_scale_32x32x64, BK=256 elems ----
// LDS buffer b (64KB @ b*65536): A [256 rows][128 B] @0, B [256 rows][128 B] @32K.
// Swizzle: 16B-chunk slot ch holds logical chunk ch ^ (row&7)  (involution).
// R7 structure (best measured): dbuf, vmcnt(0)+barrier per tile, setprio cluster.
#define BM 256
#define BN 256

__global__ __launch_bounds__(512, 2) void gemm_fused_kernel(
        const unsigned char* __restrict__ A,   // [M][Kb] fp4 (Kb bytes/row)
        const unsigned char* __restrict__ B,   // [Cpad][Kb] fp4
        const float* __restrict__ x_sq, const float* __restrict__ mu_sq,
        const int* __restrict__ y,
        float* __restrict__ pM, float* __restrict__ pS, float* __restrict__ pP,
        int Kb, int C, int NCB) {
    __shared__ __align__(16) char smem[131072];   // 2 x 64KB

    const int t  = threadIdx.x;
    const int l  = t & 63, w = t >> 6;
    const int wr = w >> 2, wc = w & 3;            // 2M x 4N waves, 128x64 each
    const int l5 = l & 31, c5 = l >> 5;           // 32x32 lane decomposition
    const int rowBase = blockIdx.x * BM;
    const int colBase = blockIdx.y * BN;
    const int nt = (Kb * 2) / 256;                // 8 K-tiles (256 elems = 128 B each)

    // ---- staging: linear LDS dest (t*16), pre-swizzled global source ----
    const int lc = (t & 7) ^ ((t >> 3) & 7);      // logical chunk this slot holds
    const unsigned char* gA = A + (size_t)(rowBase + (t >> 3)) * Kb + lc * 16;
    const unsigned char* gB = B + (size_t)(colBase + (t >> 3)) * Kb + lc * 16;

    auto STAGE = [&](int q) {
        const int qc = (q < nt) ? q : nt - 1;     // tail: harmless rewrite
        char* dst = smem + (q & 1) * 65536 + t * 16;
        const unsigned char* ga = gA + (size_t)qc * 128;
        const unsigned char* gb = gB + (size_t)qc * 128;
#pragma unroll
        for (int r = 0; r < 4; ++r)
            gload_lds16(ga + (size_t)r * 64 * Kb, dst + r * 8192);
#pragma unroll
        for (int r = 0; r < 4; ++r)
            gload_lds16(gb + (size_t)r * 64 * Kb, dst + 32768 + r * 8192);
    };

    // ---- read side: A row = wr*128 + m*32 + l5, k-granule = ks*2 + c5 ----
    // byte = row*128 + ((granule ^ (row&7)) << 4);   row&7 == l5&7
    const int swz = l5 & 7;
    const int aBase = (wr * 128 + l5) * 128;               // + m*4096 + ch
    const int bBase = 32768 + (wc * 64 + l5) * 128;        // + n*4096 + ch

    f32x16 acc[4][2];
#pragma unroll
    for (int m = 0; m < 4; ++m)
#pragma unroll
        for (int n = 0; n < 2; ++n)
#pragma unroll
            for (int j = 0; j < 16; ++j) acc[m][n][j] = 0.f;

    STAGE(0);
    asm volatile("s_waitcnt vmcnt(0)" ::: "memory");
    __builtin_amdgcn_s_barrier();

    const int SC = 0x7f7f7f7f;                    // e8m0 = 127 -> scale 1.0

#pragma unroll 1
    for (int q = 0; q < nt; ++q) {
        STAGE(q + 1);                              // into other buffer
        const char* buf = smem + (q & 1) * 65536;
#pragma unroll
        for (int ks = 0; ks < 4; ++ks) {           // four K=64 sub-steps
            const int ch = (((ks << 1) | c5) ^ swz) << 4;
            i32x4 aF[4], bF[2];
#pragma unroll
            for (int m = 0; m < 4; ++m)
                aF[m] = *(const i32x4*)(buf + aBase + m * 4096 + ch);
#pragma unroll
            for (int n = 0; n < 2; ++n)
                bF[n] = *(const i32x4*)(buf + bBase + n * 4096 + ch);
            __builtin_amdgcn_s_setprio(1);
#pragma unroll
            for (int m = 0; m < 4; ++m) {
                i32x8 a8 = __builtin_shufflevector(aF[m], aF[m], 0, 1, 2, 3, 0, 1, 2, 3);
#pragma unroll
                for (int n = 0; n < 2; ++n) {
                    i32x8 b8 = __builtin_shufflevector(bF[n], bF[n], 0, 1, 2, 3, 0, 1, 2, 3);
                    acc[m][n] = __builtin_amdgcn_mfma_scale_f32_32x32x64_f8f6f4(
                        a8, b8, acc[m][n], 4 /*fp4*/, 4 /*fp4*/, 0, SC, 0, SC);
                }
            }
            __builtin_amdgcn_s_setprio(0);
        }
        asm volatile("s_waitcnt vmcnt(0)" ::: "memory");   // next tile resident
        __builtin_amdgcn_s_barrier();
    }

    // ---- fused epilogue: per-(row, colblock) LSE partials; alias smem ----
    __syncthreads();
    float (*part)[4][3] = (float(*)[4][3])smem;   // [256 rows][4 wc][max,sum,pick]

    // C/D 32x32 layout (m101): col = lane&31, row = (reg&3) + 8*(reg>>2) + 4*(lane>>5)
#pragma unroll
    for (int m = 0; m < 4; ++m) {
#pragma unroll
        for (int j = 0; j < 16; ++j) {
            const int row_l = wr * 128 + m * 32 + (c5 << 2) + (j & 3) + ((j >> 2) << 3);
            const int grow = rowBase + row_l;
            const float xs = x_sq[grow];
            const int yr = y[grow];
            float v[2];
            float vmax = -3.4e38f, pick = -1.f;
#pragma unroll
            for (int n = 0; n < 2; ++n) {
                const int col = colBase + wc * 64 + n * 32 + l5;
                const float cr = acc[m][n][j];
                const float sq = fmaxf(xs - 2.f * cr + mu_sq[col], 0.f) * 0.5f;
                const float dd = sqrtf(sq);
                const float adj = (col == yr) ? 1.5f * dd : dd;
                if (col == yr) pick = adj;
                v[n] = (col < C) ? -adj : -1e30f;
                vmax = fmaxf(vmax, v[n]);
            }
            for (int off = 1; off <= 16; off <<= 1)
                vmax = fmaxf(vmax, __shfl_xor(vmax, off, 64));
            float s = 0.f;
#pragma unroll
            for (int n = 0; n < 2; ++n) s += expf(v[n] - vmax);
            for (int off = 1; off <= 16; off <<= 1) s += __shfl_xor(s, off, 64);
            for (int off = 1; off <= 16; off <<= 1)
                pick = fmaxf(pick, __shfl_xor(pick, off, 64));
            if (l5 == 0) {                         // lanes 0 and 32: distinct rows
                part[row_l][wc][0] = vmax;
                part[row_l][wc][1] = s;
                part[row_l][wc][2] = pick;
            }
        }
    }
    __syncthreads();
    if (t < 256) {
        float Mx = part[t][0][0], S = 0.f, pk = part[t][0][2];
#pragma unroll
        for (int b = 1; b < 4; ++b) Mx = fmaxf(Mx, part[t][b][0]);
#pragma unroll
        for (int b = 0; b < 4; ++b) {
            S += part[t][b][1] * expf(part[t][b][0] - Mx);
            pk = fmaxf(pk, part[t][b][2]);
        }
        const size_t o = (size_t)(rowBase + t) * NCB + blockIdx.y;
        pM[o] = Mx; pS[o] = S; pP[o] = pk;
    }
}

// ---- pass 3: merge colblock partials -> per-row loss -> per-block sum ----
__global__ __launch_bounds__(256) void loss_combine_kernel(
        const float* __restrict__ pM, const float* __restrict__ pS,
        const float* __restrict__ pP, float* __restrict__ bsum, int NCB) {
    const int t = threadIdx.x;
    const int row = blockIdx.x * 256 + t;
    float Mx = -3.4e38f;
    for (int b = 0; b < NCB; ++b) Mx = fmaxf(Mx, pM[(size_t)row * NCB + b]);
    float S = 0.f, pick = -1.f;
    for (int b = 0; b < NCB; ++b) {
        S += pS[(size_t)row * NCB + b] * expf(pM[(size_t)row * NCB + b] - Mx);
        pick = fmaxf(pick, pP[(size_t)row * NCB + b]);
    }
    float loss = pick + logf(S) + Mx;
    for (int off = 32; off; off >>= 1) loss += __shfl_down(loss, off, 64);
    __shared__ float sb[4];
    if ((t & 63) == 0) sb[t >> 6] = loss;
    __syncthreads();
    if (t == 0) bsum[blockIdx.x] = sb[0] + sb[1] + sb[2] + sb[3];
}

__global__ __launch_bounds__(64) void final_mean_kernel(
        const float* __restrict__ bsum, float* __restrict__ out, int nb, int N) {
    float a = 0.f;
    for (int i = threadIdx.x; i < nb; i += 64) a += bsum[i];
    for (int off = 32; off; off >>= 1) a += __shfl_down(a, off, 64);
    if (threadIdx.x == 0) out[0] = a / (float)N;
}

extern "C" void kernel_launch(void* const* d_in, const int* in_sizes, int n_in,
                              void* d_out, int out_size, void* d_ws, size_t ws_size,
                              hipStream_t stream) {
    const float* x  = (const float*)d_in[0];
    const int*   y  = (const int*)d_in[1];
    const float* mu = (const float*)d_in[2];

    const int N = in_sizes[1];                 // 16384
    const int D = in_sizes[0] / N;             // 2048
    const int C = in_sizes[2] / D;             // 1000
    const int Cpad = ((C + 255) / 256) * 256;  // 1024
    const int NCB = Cpad / BN;                 // 4 column blocks
    const int NRB = N / 256;                   // 64 row blocks
    const int Kb = D / 2;                      // fp4 bytes per row (1024)

    char* ws = (char*)d_ws;
    unsigned char* x4  = (unsigned char*)ws;  ws += (size_t)N * Kb;       // 16.8 MB
    unsigned char* mu4 = (unsigned char*)ws;  ws += (size_t)Cpad * Kb;    //  1.0 MB
    float* x_sq  = (float*)ws;                ws += (size_t)N * 4;
    float* mu_sq = (float*)ws;                ws += (size_t)Cpad * 4;
    float* pM    = (float*)ws;                ws += (size_t)N * NCB * 4;
    float* pS    = (float*)ws;                ws += (size_t)N * NCB * 4;
    float* pP    = (float*)ws;                ws += (size_t)N * NCB * 4;
    float* bsum  = (float*)ws;                ws += (size_t)NRB * 4;

    convert_kernel<<<N + Cpad, 256, 0, stream>>>(
        x, mu, (unsigned int*)x4, (unsigned int*)mu4, x_sq, mu_sq, D, N, C, Cpad);
    gemm_fused_kernel<<<dim3(N / BM, Cpad / BN), 512, 0, stream>>>(
        x4, mu4, x_sq, mu_sq, y, pM, pS, pP, Kb, C, NCB);
    loss_combine_kernel<<<NRB, 256, 0, stream>>>(pM, pS, pP, bsum, NCB);
    final_mean_kernel<<<1, 64, 0, stream>>>(bsum, d_out ? (float*)d_out : nullptr, NRB, N);
}

// Round 11
// 72.906 us; speedup vs baseline: 1.2371x; 1.2371x over previous
//
#include <hip/hip_runtime.h>

typedef float f32x4  __attribute__((ext_vector_type(4)));
typedef int   i32x4  __attribute__((ext_vector_type(4)));
typedef int   i32x8  __attribute__((ext_vector_type(8)));

__device__ inline void gload_lds16(const void* g, void* l) {
    __builtin_amdgcn_global_load_lds((const __attribute__((address_space(1))) void*)g,
                                     (__attribute__((address_space(3))) void*)l,
                                     16, 0, 0);
}

// f32 -> fp4 e2m1 (RNE via threshold ladder): values {0,.5,1,1.5,2,3,4,6}
__device__ inline unsigned int enc_fp4(float v) {
    float a = fabsf(v);
    unsigned int c = (unsigned int)(a > 0.25f) + (a > 0.75f) + (a > 1.25f) +
                     (a > 1.75f) + (a > 2.5f)  + (a > 3.5f)  + (a > 5.0f);
    return c | ((v < 0.f) ? 8u : 0u);
}

// ---- pass 1: {x, mu} f32 -> fp4, plus exact f32 sum-of-squares per row ----
__global__ __launch_bounds__(256) void convert_kernel(
        const float* __restrict__ x, const float* __restrict__ mu,
        unsigned int* __restrict__ x4, unsigned int* __restrict__ mu4,
        float* __restrict__ x_sq, float* __restrict__ mu_sq,
        int D, int N, int C, int Cpad) {
    const int bid = blockIdx.x;
    const int t = threadIdx.x;
    const bool isX = bid < N;
    const int r = isX ? bid : bid - N;

    unsigned int* out = (isX ? x4 : mu4) + (size_t)r * (D / 8) + t;
    if (!isX && r >= C) {
        *out = 0u;
        if (t == 0) mu_sq[r] = 0.f;
        return;
    }
    const float* src = (isX ? x + (size_t)r * D : mu + (size_t)r * D) + t * 8;
    float4 v0 = *(const float4*)(src);
    float4 v1 = *(const float4*)(src + 4);
    float acc = v0.x * v0.x + v0.y * v0.y + v0.z * v0.z + v0.w * v0.w
              + v1.x * v1.x + v1.y * v1.y + v1.z * v1.z + v1.w * v1.w;
    unsigned int p = enc_fp4(v0.x) | (enc_fp4(v0.y) << 4) | (enc_fp4(v0.z) << 8)
                   | (enc_fp4(v0.w) << 12) | (enc_fp4(v1.x) << 16)
                   | (enc_fp4(v1.y) << 20) | (enc_fp4(v1.z) << 24)
                   | (enc_fp4(v1.w) << 28);
    *out = p;

    for (int off = 32; off; off >>= 1) acc += __shfl_down(acc, off, 64);
    __shared__ float sbuf[4];
    if ((t & 63) == 0) sbuf[t >> 6] = acc;
    __syncthreads();
    if (t == 0) {
        float s = sbuf[0] + sbuf[1] + sbuf[2] + sbuf[3];
        if (isX) x_sq[r] = s; else mu_sq[r] = s;
    }
}

// ---- pass 2: 128x256 fp4 GEMM, BK=128 elems (64B rows), 2 blocks/CU ----
// LDS buffer b (24KB @ b*24576): A [128 rows][64 B] @0, B [256 rows][64 B] @8K.
// Swizzle: 16B-chunk slot ch holds logical chunk ch ^ (row&3)  (involution).
// R7 loop structure (dbuf, stage-at-top, vmcnt(0)+barrier per tile).
// 64 VGPR acc (64x64/wave) + launch_bounds(512,4) -> 16 waves/CU, 4/SIMD.
#define BM 128
#define BN 256

__global__ __launch_bounds__(512, 4) void gemm_fused_kernel(
        const unsigned char* __restrict__ A,   // [M][Kb] fp4 (Kb bytes/row)
        const unsigned char* __restrict__ B,   // [Cpad][Kb] fp4
        const float* __restrict__ x_sq, const float* __restrict__ mu_sq,
        const int* __restrict__ y,
        float* __restrict__ pM, float* __restrict__ pS, float* __restrict__ pP,
        int Kb, int C, int NCB) {
    __shared__ __align__(16) char smem[49152];    // 2 x 24KB

    const int t  = threadIdx.x;
    const int l  = t & 63, w = t >> 6;
    const int wr = w >> 2, wc = w & 3;            // 2M x 4N waves, 64x64 each
    const int lr = l & 15, kh = l >> 4;
    const int rowBase = blockIdx.x * BM;
    const int colBase = blockIdx.y * BN;
    const int nt = Kb / 64;                       // 16 K-tiles (128 elems = 64 B each)

    // ---- staging: linear LDS dest (t*16), pre-swizzled global source ----
    // slot: row = t>>2 (+128/round for B), phys chunk = t&3
    const int lc = (t & 3) ^ ((t >> 2) & 3);      // logical chunk this slot holds
    const unsigned char* gA = A + (size_t)(rowBase + (t >> 2)) * Kb + lc * 16;
    const unsigned char* gB = B + (size_t)(colBase + (t >> 2)) * Kb + lc * 16;

    auto STAGE = [&](int q) {
        const int qc = (q < nt) ? q : nt - 1;     // tail: harmless rewrite
        char* dst = smem + (q & 1) * 24576 + t * 16;
        const size_t ko = (size_t)qc * 64;
        gload_lds16(gA + ko, dst);                               // A: 128 rows
#pragma unroll
        for (int r = 0; r < 2; ++r)                              // B: 256 rows
            gload_lds16(gB + ko + (size_t)r * 128 * Kb, dst + 8192 + r * 8192);
    };

    // ---- read side: conflict-free swizzled ds_read_b128 ----
    const int pch = (kh ^ (lr & 3)) << 4;
    const int aBase = (wr * 64 + lr) * 64 + pch;             // + m*1024
    const int bBase = 8192 + (wc * 64 + lr) * 64 + pch;      // + n*1024

    f32x4 acc[4][4];
#pragma unroll
    for (int m = 0; m < 4; ++m)
#pragma unroll
        for (int n = 0; n < 4; ++n) acc[m][n] = (f32x4){0.f, 0.f, 0.f, 0.f};

    STAGE(0);
    asm volatile("s_waitcnt vmcnt(0)" ::: "memory");
    __builtin_amdgcn_s_barrier();

    const int SC = 0x7f7f7f7f;                    // e8m0 = 127 -> scale 1.0

#pragma unroll 1
    for (int q = 0; q < nt; ++q) {
        STAGE(q + 1);                              // into other buffer
        const char* buf = smem + (q & 1) * 24576;
        i32x4 aF[4], bF[4];
#pragma unroll
        for (int m = 0; m < 4; ++m)
            aF[m] = *(const i32x4*)(buf + aBase + m * 1024);
#pragma unroll
        for (int n = 0; n < 4; ++n)
            bF[n] = *(const i32x4*)(buf + bBase + n * 1024);
        asm volatile("s_waitcnt lgkmcnt(0)" ::: "memory");
        __builtin_amdgcn_sched_barrier(0);
        __builtin_amdgcn_s_setprio(1);
#pragma unroll
        for (int m = 0; m < 4; ++m) {
            i32x8 a8 = __builtin_shufflevector(aF[m], aF[m], 0, 1, 2, 3, 0, 1, 2, 3);
#pragma unroll
            for (int n = 0; n < 4; ++n) {
                i32x8 b8 = __builtin_shufflevector(bF[n], bF[n], 0, 1, 2, 3, 0, 1, 2, 3);
                acc[m][n] = __builtin_amdgcn_mfma_scale_f32_16x16x128_f8f6f4(
                    a8, b8, acc[m][n], 4 /*fp4*/, 4 /*fp4*/, 0, SC, 0, SC);
            }
        }
        __builtin_amdgcn_s_setprio(0);
        asm volatile("s_waitcnt vmcnt(0)" ::: "memory");   // next tile resident
        __builtin_amdgcn_s_barrier();
    }

    // ---- fused epilogue: per-(row, colblock) LSE partials; alias smem ----
    __syncthreads();
    float (*part)[4][3] = (float(*)[4][3])smem;   // [128 rows][4 wc][max,sum,pick]

    // C/D layout: col = lane&15 (lr), row = kh*4 + reg j
#pragma unroll
    for (int m = 0; m < 4; ++m) {
#pragma unroll
        for (int j = 0; j < 4; ++j) {
            const int row_l = wr * 64 + m * 16 + kh * 4 + j;
            const int grow = rowBase + row_l;
            const float xs = x_sq[grow];
            const int yr = y[grow];
            float v[4];
            float vmax = -3.4e38f, pick = -1.f;
#pragma unroll
            for (int n = 0; n < 4; ++n) {
                const int col = colBase + wc * 64 + n * 16 + lr;
                const float cr = acc[m][n][j];
                const float sq = fmaxf(xs - 2.f * cr + mu_sq[col], 0.f) * 0.5f;
                const float dd = sqrtf(sq);
                const float adj = (col == yr) ? 1.5f * dd : dd;
                if (col == yr) pick = adj;
                v[n] = (col < C) ? -adj : -1e30f;
                vmax = fmaxf(vmax, v[n]);
            }
            for (int off = 1; off <= 8; off <<= 1)
                vmax = fmaxf(vmax, __shfl_xor(vmax, off, 64));
            float s = 0.f;
#pragma unroll
            for (int n = 0; n < 4; ++n) s += expf(v[n] - vmax);
            for (int off = 1; off <= 8; off <<= 1) s += __shfl_xor(s, off, 64);
            for (int off = 1; off <= 8; off <<= 1)
                pick = fmaxf(pick, __shfl_xor(pick, off, 64));
            if (lr == 0) {
                part[row_l][wc][0] = vmax;
                part[row_l][wc][1] = s;
                part[row_l][wc][2] = pick;
            }
        }
    }
    __syncthreads();
    if (t < 128) {
        float Mx = part[t][0][0], S = 0.f, pk = part[t][0][2];
#pragma unroll
        for (int b = 1; b < 4; ++b) Mx = fmaxf(Mx, part[t][b][0]);
#pragma unroll
        for (int b = 0; b < 4; ++b) {
            S += part[t][b][1] * expf(part[t][b][0] - Mx);
            pk = fmaxf(pk, part[t][b][2]);
        }
        const size_t o = (size_t)(rowBase + t) * NCB + blockIdx.y;
        pM[o] = Mx; pS[o] = S; pP[o] = pk;
    }
}

// ---- pass 3: merge colblock partials -> per-row loss -> per-block sum ----
__global__ __launch_bounds__(256) void loss_combine_kernel(
        const float* __restrict__ pM, const float* __restrict__ pS,
        const float* __restrict__ pP, float* __restrict__ bsum, int NCB) {
    const int t = threadIdx.x;
    const int row = blockIdx.x * 256 + t;
    float Mx = -3.4e38f;
    for (int b = 0; b < NCB; ++b) Mx = fmaxf(Mx, pM[(size_t)row * NCB + b]);
    float S = 0.f, pick = -1.f;
    for (int b = 0; b < NCB; ++b) {
        S += pS[(size_t)row * NCB + b] * expf(pM[(size_t)row * NCB + b] - Mx);
        pick = fmaxf(pick, pP[(size_t)row * NCB + b]);
    }
    float loss = pick + logf(S) + Mx;
    for (int off = 32; off; off >>= 1) loss += __shfl_down(loss, off, 64);
    __shared__ float sb[4];
    if ((t & 63) == 0) sb[t >> 6] = loss;
    __syncthreads();
    if (t == 0) bsum[blockIdx.x] = sb[0] + sb[1] + sb[2] + sb[3];
}

__global__ __launch_bounds__(64) void final_mean_kernel(
        const float* __restrict__ bsum, float* __restrict__ out, int nb, int N) {
    float a = 0.f;
    for (int i = threadIdx.x; i < nb; i += 64) a += bsum[i];
    for (int off = 32; off; off >>= 1) a += __shfl_down(a, off, 64);
    if (threadIdx.x == 0) out[0] = a / (float)N;
}

extern "C" void kernel_launch(void* const* d_in, const int* in_sizes, int n_in,
                              void* d_out, int out_size, void* d_ws, size_t ws_size,
                              hipStream_t stream) {
    const float* x  = (const float*)d_in[0];
    const int*   y  = (const int*)d_in[1];
    const float* mu = (const float*)d_in[2];

    const int N = in_sizes[1];                 // 16384
    const int D = in_sizes[0] / N;             // 2048
    const int C = in_sizes[2] / D;             // 1000
    const int Cpad = ((C + 255) / 256) * 256;  // 1024
    const int NCB = Cpad / BN;                 // 4 column blocks
    const int NRB = N / 256;                   // 64 row blocks
    const int Kb = D / 2;                      // fp4 bytes per row (1024)

    char* ws = (char*)d_ws;
    unsigned char* x4  = (unsigned char*)ws;  ws += (size_t)N * Kb;       // 16.8 MB
    unsigned char* mu4 = (unsigned char*)ws;  ws += (size_t)Cpad * Kb;    //  1.0 MB
    float* x_sq  = (float*)ws;                ws += (size_t)N * 4;
    float* mu_sq = (float*)ws;                ws += (size_t)Cpad * 4;
    float* pM    = (float*)ws;                ws += (size_t)N * NCB * 4;
    float* pS    = (float*)ws;                ws += (size_t)N * NCB * 4;
    float* pP    = (float*)ws;                ws += (size_t)N * NCB * 4;
    float* bsum  = (float*)ws;                ws += (size_t)NRB * 4;

    convert_kernel<<<N + Cpad, 256, 0, stream>>>(
        x, mu, (unsigned int*)x4, (unsigned int*)mu4, x_sq, mu_sq, D, N, C, Cpad);
    gemm_fused_kernel<<<dim3(N / BM, Cpad / BN), 512, 0, stream>>>(
        x4, mu4, x_sq, mu_sq, y, pM, pS, pP, Kb, C, NCB);
    loss_combine_kernel<<<NRB, 256, 0, stream>>>(pM, pS, pP, bsum, NCB);
    final_mean_kernel<<<1, 64, 0, stream>>>(bsum, d_out ? (float*)d_out : nullptr, NRB, N);
}

// Round 12
// 72.152 us; speedup vs baseline: 1.2501x; 1.0105x over previous
//
#include <hip/hip_runtime.h>

typedef float f32x4  __attribute__((ext_vector_type(4)));
typedef int   i32x4  __attribute__((ext_vector_type(4)));
typedef int   i32x8  __attribute__((ext_vector_type(8)));

__device__ inline void gload_lds16(const void* g, void* l) {
    __builtin_amdgcn_global_load_lds((const __attribute__((address_space(1))) void*)g,
                                     (__attribute__((address_space(3))) void*)l,
                                     16, 0, 0);
}

// f32 -> fp4 e2m1 (RNE via threshold ladder): values {0,.5,1,1.5,2,3,4,6}
__device__ inline unsigned int enc_fp4(float v) {
    float a = fabsf(v);
    unsigned int c = (unsigned int)(a > 0.25f) + (a > 0.75f) + (a > 1.25f) +
                     (a > 1.75f) + (a > 2.5f)  + (a > 3.5f)  + (a > 5.0f);
    return c | ((v < 0.f) ? 8u : 0u);
}

// ---- pass 1: {x, mu} f32 -> fp4, plus exact f32 sum-of-squares per row ----
__global__ __launch_bounds__(256) void convert_kernel(
        const float* __restrict__ x, const float* __restrict__ mu,
        unsigned int* __restrict__ x4, unsigned int* __restrict__ mu4,
        float* __restrict__ x_sq, float* __restrict__ mu_sq,
        int D, int N, int C, int Cpad) {
    const int bid = blockIdx.x;
    const int t = threadIdx.x;
    const bool isX = bid < N;
    const int r = isX ? bid : bid - N;

    unsigned int* out = (isX ? x4 : mu4) + (size_t)r * (D / 8) + t;
    if (!isX && r >= C) {
        *out = 0u;
        if (t == 0) mu_sq[r] = 0.f;
        return;
    }
    const float* src = (isX ? x + (size_t)r * D : mu + (size_t)r * D) + t * 8;
    float4 v0 = *(const float4*)(src);
    float4 v1 = *(const float4*)(src + 4);
    float acc = v0.x * v0.x + v0.y * v0.y + v0.z * v0.z + v0.w * v0.w
              + v1.x * v1.x + v1.y * v1.y + v1.z * v1.z + v1.w * v1.w;
    unsigned int p = enc_fp4(v0.x) | (enc_fp4(v0.y) << 4) | (enc_fp4(v0.z) << 8)
                   | (enc_fp4(v0.w) << 12) | (enc_fp4(v1.x) << 16)
                   | (enc_fp4(v1.y) << 20) | (enc_fp4(v1.z) << 24)
                   | (enc_fp4(v1.w) << 28);
    *out = p;

    for (int off = 32; off; off >>= 1) acc += __shfl_down(acc, off, 64);
    __shared__ float sbuf[4];
    if ((t & 63) == 0) sbuf[t >> 6] = acc;
    __syncthreads();
    if (t == 0) {
        float s = sbuf[0] + sbuf[1] + sbuf[2] + sbuf[3];
        if (isX) x_sq[r] = s; else mu_sq[r] = s;
    }
}

// ---- pass 2: 128x256 fp4 GEMM, BK=128 elems (64B rows), 2 blocks/CU ----
// LDS buffer b (24KB @ b*24576): A [128 rows][64 B] @0, B [256 rows][64 B] @8K.
// Swizzle: 16B-chunk slot ch holds logical chunk ch ^ (row&3)  (involution).
// R11 structure minus self-inflicted pins: no lgkm pin / sched_barrier / setprio;
// compiler emits fine-grained lgkmcnt (m97-verified). Undef-high fp4 operands.
#define BM 128
#define BN 256

__global__ __launch_bounds__(512, 4) void gemm_fused_kernel(
        const unsigned char* __restrict__ A,   // [M][Kb] fp4 (Kb bytes/row)
        const unsigned char* __restrict__ B,   // [Cpad][Kb] fp4
        const float* __restrict__ x_sq, const float* __restrict__ mu_sq,
        const int* __restrict__ y,
        float* __restrict__ pM, float* __restrict__ pS, float* __restrict__ pP,
        int Kb, int C, int NCB) {
    __shared__ __align__(16) char smem[49152];    // 2 x 24KB

    const int t  = threadIdx.x;
    const int l  = t & 63, w = t >> 6;
    const int wr = w >> 2, wc = w & 3;            // 2M x 4N waves, 64x64 each
    const int lr = l & 15, kh = l >> 4;
    const int rowBase = blockIdx.x * BM;
    const int colBase = blockIdx.y * BN;
    const int nt = Kb / 64;                       // 16 K-tiles (128 elems = 64 B each)

    // ---- staging: linear LDS dest (t*16), pre-swizzled global source ----
    const int lc = (t & 3) ^ ((t >> 2) & 3);      // logical chunk this slot holds
    const unsigned char* gA = A + (size_t)(rowBase + (t >> 2)) * Kb + lc * 16;
    const unsigned char* gB = B + (size_t)(colBase + (t >> 2)) * Kb + lc * 16;

    auto STAGE = [&](int q) {
        const int qc = (q < nt) ? q : nt - 1;     // tail: harmless rewrite
        char* dst = smem + (q & 1) * 24576 + t * 16;
        const size_t ko = (size_t)qc * 64;
        gload_lds16(gA + ko, dst);                               // A: 128 rows
#pragma unroll
        for (int r = 0; r < 2; ++r)                              // B: 256 rows
            gload_lds16(gB + ko + (size_t)r * 128 * Kb, dst + 8192 + r * 8192);
    };

    // ---- read side: conflict-free swizzled ds_read_b128 ----
    const int pch = (kh ^ (lr & 3)) << 4;
    const int aBase = (wr * 64 + lr) * 64 + pch;             // + m*1024
    const int bBase = 8192 + (wc * 64 + lr) * 64 + pch;      // + n*1024

    f32x4 acc[4][4];
#pragma unroll
    for (int m = 0; m < 4; ++m)
#pragma unroll
        for (int n = 0; n < 4; ++n) acc[m][n] = (f32x4){0.f, 0.f, 0.f, 0.f};

    STAGE(0);
    asm volatile("s_waitcnt vmcnt(0)" ::: "memory");
    __builtin_amdgcn_s_barrier();

    const int SC = 0x7f7f7f7f;                    // e8m0 = 127 -> scale 1.0

#pragma unroll 2
    for (int q = 0; q < nt; ++q) {
        STAGE(q + 1);                              // into other buffer
        const char* buf = smem + (q & 1) * 24576;
        i32x4 aF[4], bF[4];
#pragma unroll
        for (int m = 0; m < 4; ++m)
            aF[m] = *(const i32x4*)(buf + aBase + m * 1024);
#pragma unroll
        for (int n = 0; n < 4; ++n)
            bF[n] = *(const i32x4*)(buf + bBase + n * 1024);
        // fp4 FMT reads the low 4 dwords of the 8-dword operand: upper half undef
#pragma unroll
        for (int m = 0; m < 4; ++m) {
            i32x8 a8 = __builtin_shufflevector(aF[m], aF[m], 0, 1, 2, 3, -1, -1, -1, -1);
#pragma unroll
            for (int n = 0; n < 4; ++n) {
                i32x8 b8 = __builtin_shufflevector(bF[n], bF[n], 0, 1, 2, 3, -1, -1, -1, -1);
                acc[m][n] = __builtin_amdgcn_mfma_scale_f32_16x16x128_f8f6f4(
                    a8, b8, acc[m][n], 4 /*fp4*/, 4 /*fp4*/, 0, SC, 0, SC);
            }
        }
        asm volatile("s_waitcnt vmcnt(0)" ::: "memory");   // next tile resident
        __builtin_amdgcn_s_barrier();
    }

    // ---- fused epilogue: per-(row, colblock) LSE partials; alias smem ----
    __syncthreads();
    float (*part)[4][3] = (float(*)[4][3])smem;   // [128 rows][4 wc][max,sum,pick]

    // C/D layout: col = lane&15 (lr), row = kh*4 + reg j
#pragma unroll
    for (int m = 0; m < 4; ++m) {
#pragma unroll
        for (int j = 0; j < 4; ++j) {
            const int row_l = wr * 64 + m * 16 + kh * 4 + j;
            const int grow = rowBase + row_l;
            const float xs = x_sq[grow];
            const int yr = y[grow];
            float v[4];
            float vmax = -3.4e38f, pick = -1.f;
#pragma unroll
            for (int n = 0; n < 4; ++n) {
                const int col = colBase + wc * 64 + n * 16 + lr;
                const float cr = acc[m][n][j];
                const float sq = fmaxf(xs - 2.f * cr + mu_sq[col], 0.f) * 0.5f;
                const float dd = sqrtf(sq);
                const float adj = (col == yr) ? 1.5f * dd : dd;
                if (col == yr) pick = adj;
                v[n] = (col < C) ? -adj : -1e30f;
                vmax = fmaxf(vmax, v[n]);
            }
            for (int off = 1; off <= 8; off <<= 1)
                vmax = fmaxf(vmax, __shfl_xor(vmax, off, 64));
            float s = 0.f;
#pragma unroll
            for (int n = 0; n < 4; ++n) s += expf(v[n] - vmax);
            for (int off = 1; off <= 8; off <<= 1) s += __shfl_xor(s, off, 64);
            for (int off = 1; off <= 8; off <<= 1)
                pick = fmaxf(pick, __shfl_xor(pick, off, 64));
            if (lr == 0) {
                part[row_l][wc][0] = vmax;
                part[row_l][wc][1] = s;
                part[row_l][wc][2] = pick;
            }
        }
    }
    __syncthreads();
    if (t < 128) {
        float Mx = part[t][0][0], S = 0.f, pk = part[t][0][2];
#pragma unroll
        for (int b = 1; b < 4; ++b) Mx = fmaxf(Mx, part[t][b][0]);
#pragma unroll
        for (int b = 0; b < 4; ++b) {
            S += part[t][b][1] * expf(part[t][b][0] - Mx);
            pk = fmaxf(pk, part[t][b][2]);
        }
        const size_t o = (size_t)(rowBase + t) * NCB + blockIdx.y;
        pM[o] = Mx; pS[o] = S; pP[o] = pk;
    }
}

// ---- pass 3: merge colblock partials -> per-row loss -> per-block sum ----
__global__ __launch_bounds__(256) void loss_combine_kernel(
        const float* __restrict__ pM, const float* __restrict__ pS,
        const float* __restrict__ pP, float* __restrict__ bsum, int NCB) {
    const int t = threadIdx.x;
    const int row = blockIdx.x * 256 + t;
    float Mx = -3.4e38f;
    for (int b = 0; b < NCB; ++b) Mx = fmaxf(Mx, pM[(size_t)row * NCB + b]);
    float S = 0.f, pick = -1.f;
    for (int b = 0; b < NCB; ++b) {
        S += pS[(size_t)row * NCB + b] * expf(pM[(size_t)row * NCB + b] - Mx);
        pick = fmaxf(pick, pP[(size_t)row * NCB + b]);
    }
    float loss = pick + logf(S) + Mx;
    for (int off = 32; off; off >>= 1) loss += __shfl_down(loss, off, 64);
    __shared__ float sb[4];
    if ((t & 63) == 0) sb[t >> 6] = loss;
    __syncthreads();
    if (t == 0) bsum[blockIdx.x] = sb[0] + sb[1] + sb[2] + sb[3];
}

__global__ __launch_bounds__(64) void final_mean_kernel(
        const float* __restrict__ bsum, float* __restrict__ out, int nb, int N) {
    float a = 0.f;
    for (int i = threadIdx.x; i < nb; i += 64) a += bsum[i];
    for (int off = 32; off; off >>= 1) a += __shfl_down(a, off, 64);
    if (threadIdx.x == 0) out[0] = a / (float)N;
}

extern "C" void kernel_launch(void* const* d_in, const int* in_sizes, int n_in,
                              void* d_out, int out_size, void* d_ws, size_t ws_size,
                              hipStream_t stream) {
    const float* x  = (const float*)d_in[0];
    const int*   y  = (const int*)d_in[1];
    const float* mu = (const float*)d_in[2];

    const int N = in_sizes[1];                 // 16384
    const int D = in_sizes[0] / N;             // 2048
    const int C = in_sizes[2] / D;             // 1000
    const int Cpad = ((C + 255) / 256) * 256;  // 1024
    const int NCB = Cpad / BN;                 // 4 column blocks
    const int NRB = N / 256;                   // 64 row blocks
    const int Kb = D / 2;                      // fp4 bytes per row (1024)

    char* ws = (char*)d_ws;
    unsigned char* x4  = (unsigned char*)ws;  ws += (size_t)N * Kb;       // 16.8 MB
    unsigned char* mu4 = (unsigned char*)ws;  ws += (size_t)Cpad * Kb;    //  1.0 MB
    float* x_sq  = (float*)ws;                ws += (size_t)N * 4;
    float* mu_sq = (float*)ws;                ws += (size_t)Cpad * 4;
    float* pM    = (float*)ws;                ws += (size_t)N * NCB * 4;
    float* pS    = (float*)ws;                ws += (size_t)N * NCB * 4;
    float* pP    = (float*)ws;                ws += (size_t)N * NCB * 4;
    float* bsum  = (float*)ws;                ws += (size_t)NRB * 4;

    convert_kernel<<<N + Cpad, 256, 0, stream>>>(
        x, mu, (unsigned int*)x4, (unsigned int*)mu4, x_sq, mu_sq, D, N, C, Cpad);
    gemm_fused_kernel<<<dim3(N / BM, Cpad / BN), 512, 0, stream>>>(
        x4, mu4, x_sq, mu_sq, y, pM, pS, pP, Kb, C, NCB);
    loss_combine_kernel<<<NRB, 256, 0, stream>>>(pM, pS, pP, bsum, NCB);
    final_mean_kernel<<<1, 64, 0, stream>>>(bsum, d_out ? (float*)d_out : nullptr, NRB, N);
}